// Round 13
// baseline (141.827 us; speedup 1.0000x reference)
//
#include <hip/hip_runtime.h>
#include <math.h>

#define A_NUM 8732
#define O_NUM 32
#define NEGPOS 3
#define NTHR 256
#define NWAVE 4
#define ASPLIT 4
#define APB 2183                       // 8732/4 exactly
#define K_ANCH 9                       // 9*256 = 2304 >= 2183
#define LOGEPS_F (-27.631021115928547f)

__device__ __forceinline__ unsigned int rotu(unsigned int v) {
    // row_ror:1 (0x121): rotate by 1 within each 16-lane row
    return (unsigned int)__builtin_amdgcn_update_dpp((int)v, (int)v, 0x121, 0xf, 0xf, false);
}
__device__ __forceinline__ float rotf(float v) {
    return __int_as_float((int)rotu((unsigned int)__float_as_int(v)));
}

// top-18 bits of IoU as a uint (IoU >= 0 so uint order == float order)
__device__ __forceinline__ unsigned int iou_hi(float tx1, float ty1, float tx2, float ty2, float ta,
                                               float px1, float py1, float px2, float py2, float ap) {
    float w = __saturatef(fminf(tx2, px2) - fmaxf(tx1, px1));
    float h = __saturatef(fminf(ty2, py2) - fmaxf(ty1, py1));
    float inter = w * h;
    float uni = (ta + ap) - inter;
    float iou = inter * __builtin_amdgcn_rcpf(uni);
    return __float_as_uint(iou) & 0xFFFFC000u;
}

__device__ __forceinline__ float sl1_sum(float4 t, float4 pr, float4 ld) {
    float gx = ((t.x + t.z) * 0.5f - pr.x) / (0.1f * pr.z);
    float gy = ((t.y + t.w) * 0.5f - pr.y) / (0.1f * pr.w);
    float gw = logf((t.z - t.x) / pr.z) / 0.2f;
    float gh = logf((t.w - t.y) / pr.w) / 0.2f;
    float d0 = ld.x - gx, d1 = ld.y - gy, d2 = ld.z - gw, d3 = ld.w - gh;
    float a0 = fabsf(d0), a1 = fabsf(d1), a2 = fabsf(d2), a3 = fabsf(d3);
    float s0 = (a0 < 1.0f) ? 0.5f * d0 * d0 : a0 - 0.5f;
    float s1 = (a1 < 1.0f) ? 0.5f * d1 * d1 : a1 - 0.5f;
    float s2 = (a2 < 1.0f) ? 0.5f * d2 * d2 : a2 - 0.5f;
    float s3 = (a3 < 1.0f) ? 0.5f * d3 * d3 : a3 - 0.5f;
    return s0 + s1 + s2 + s3;
}

__device__ __forceinline__ float bce_pos(int pred, float tgt) {
    float logp   = (pred == 0) ? LOGEPS_F : 0.0f;
    float log1mp = (pred == 1) ? LOGEPS_F : 0.0f;
    return -(tgt * logp + (1.0f - tgt) * log1mp);
}

// K1: grid = (ASPLIT, BF) = 1024 blocks of 256 threads (4 waves). (R11 exact.)
__global__ __launch_bounds__(NTHR) void mfbl_k1(
    const float* __restrict__ loc_data, const float* __restrict__ conf_data,
    const float* __restrict__ anchors, const float* __restrict__ targets,
    unsigned int* __restrict__ g_tred, float4* __restrict__ g_part)
{
    const int split = blockIdx.x;
    const int frame = blockIdx.y;
    const int a_lo = split * APB;
    const int nA = min(a_lo + APB, A_NUM) - a_lo;   // 2183
    const int tid = threadIdx.x;
    const int lane = tid & 63;
    const int wid  = tid >> 6;
    const int r = lane >> 4;                         // row 0..3
    const int i = lane & 15;                         // in-row pos

    __shared__ float4 s_tc[O_NUM];
    __shared__ float  s_lab[O_NUM];
    __shared__ unsigned int s_tred[O_NUM][NWAVE];
    __shared__ float s_r[4][NWAVE];

    if (tid < O_NUM) {
        const float* t = targets + ((size_t)frame * O_NUM + tid) * 5;
        s_tc[tid] = make_float4(t[0], t[1], t[2], t[3]);
        s_lab[tid] = t[4];
    }

    float px1[K_ANCH], py1[K_ANCH], px2[K_ANCH], py2[K_ANCH], ap[K_ANCH];
    unsigned int bestA[K_ANCH];
#pragma unroll
    for (int k = 0; k < K_ANCH; ++k) {
        int idx = tid + k * NTHR;
        int ic = min(idx, nA - 1);
        float4 pr = *(const float4*)(anchors + (size_t)(a_lo + ic) * 4);
        float hw = pr.z * 0.5f, hh = pr.w * 0.5f;
        px1[k] = pr.x - hw; py1[k] = pr.y - hh;
        px2[k] = pr.x + hw; py2[k] = pr.y + hh;
        ap[k] = (px2[k] - px1[k]) * (py2[k] - py1[k]);
        bestA[k] = 0u;
    }
    const unsigned int aT0 = 16383u - (unsigned int)(a_lo + tid);  // aT[k] = aT0 - k*NTHR
    __syncthreads();

    unsigned int tbp[2];
    for (int p = 0; p < 2; ++p) {
        const int t0 = (((r + p) & 1) << 4) | i;     // my starting truth
        float4 tc = s_tc[t0];
        float ta = (tc.z - tc.x) * (tc.w - tc.y);
        unsigned int oc = (unsigned int)(31 - t0);
        unsigned int tb = 0u;
        for (int s = 0; s < 16; ++s) {
#pragma unroll
            for (int k = 0; k < K_ANCH; ++k) {
                unsigned int hi = iou_hi(tc.x, tc.y, tc.z, tc.w, ta,
                                         px1[k], py1[k], px2[k], py2[k], ap[k]);
                bestA[k] = max(bestA[k], hi | oc);
                tb = max(tb, hi | (aT0 - (unsigned int)(k * NTHR)));
            }
            tc.x = rotf(tc.x); tc.y = rotf(tc.y);
            tc.z = rotf(tc.z); tc.w = rotf(tc.w);
            ta = rotf(ta); oc = rotu(oc); tb = rotu(tb);
        }
        tbp[p] = tb;   // 16 rotations = identity: tb is home
    }

    unsigned int v = max(tbp[0], (unsigned int)__shfl_xor((int)tbp[1], 16));
    v = max(v, (unsigned int)__shfl_xor((int)v, 32));
    if (lane < O_NUM) s_tred[lane][wid] = v;
    __syncthreads();
    if (tid < O_NUM) {
        unsigned int k = s_tred[tid][0];
        for (int w = 1; w < NWAVE; ++w) k = max(k, s_tred[tid][w]);
        atomicMax(&g_tred[(size_t)frame * O_NUM + tid], k);
    }

    float l_sum = 0.0f, cpos = 0.0f, np_cnt = 0.0f, m_cnt = 0.0f;
#pragma unroll
    for (int k = 0; k < K_ANCH; ++k) {
        int idx = tid + k * NTHR;
        if (idx < nA) {
            unsigned int key = bestA[k];
            int bo = 31 - (int)(key & 31u);
            unsigned int hi = key & 0xFFFFC000u;
            int a = a_lo + idx;
            const float2 cdv = *(const float2*)(conf_data + ((size_t)frame * A_NUM + a) * 2);
            int pred = (cdv.y > cdv.x) ? 1 : 0;
            int cv = (hi >= 0x3F000000u) ? (int)s_lab[bo] + 1 : 0;
            if (cv > 0) {
                np_cnt += 1.0f;
                float4 pr = *(const float4*)(anchors + (size_t)a * 4);
                float4 ld = *(const float4*)(loc_data + ((size_t)frame * A_NUM + a) * 4);
                l_sum += sl1_sum(s_tc[bo], pr, ld);
                cpos += bce_pos(pred, (float)cv);
            } else {
                m_cnt += (float)pred;
            }
        }
    }
    for (int s = 32; s > 0; s >>= 1) {
        l_sum  += __shfl_down(l_sum, s);
        cpos   += __shfl_down(cpos, s);
        np_cnt += __shfl_down(np_cnt, s);
        m_cnt  += __shfl_down(m_cnt, s);
    }
    if (lane == 0) { s_r[0][wid] = l_sum; s_r[1][wid] = cpos; s_r[2][wid] = np_cnt; s_r[3][wid] = m_cnt; }
    __syncthreads();
    if (tid == 0) {
        float L = 0, C = 0, NP = 0, M = 0;
        for (int w = 0; w < NWAVE; ++w) { L += s_r[0][w]; C += s_r[1][w]; NP += s_r[2][w]; M += s_r[3][w]; }
        g_part[frame * ASPLIT + split] = make_float4(L, C, NP, M);
    }
}

// K2: forced-match corrections + finalize (validated, unchanged).
__global__ __launch_bounds__(256) void mfbl_k2(
    const float* __restrict__ loc_data, const float* __restrict__ conf_data,
    const float* __restrict__ anchors, const float* __restrict__ targets,
    const unsigned int* __restrict__ g_tred, const float4* __restrict__ g_part,
    float* __restrict__ ws_l, float* __restrict__ ws_c)
{
    const int lane = threadIdx.x & 63;
    const int wid  = threadIdx.x >> 6;
    const int frame = blockIdx.x * 4 + wid;

    __shared__ float4 s_tc[4][O_NUM];
    __shared__ float s_ta[4][O_NUM], s_lab[4][O_NUM];
    __shared__ int s_bp[4][O_NUM];

    if (lane < O_NUM) {
        const float* t = targets + ((size_t)frame * O_NUM + lane) * 5;
        float x1 = t[0], y1 = t[1], x2 = t[2], y2 = t[3];
        s_tc[wid][lane] = make_float4(x1, y1, x2, y2);
        s_ta[wid][lane] = (x2 - x1) * (y2 - y1);
        s_lab[wid][lane] = t[4];
        unsigned int k = g_tred[(size_t)frame * O_NUM + lane];
        s_bp[wid][lane] = 16383 - (int)(k & 16383u);
    }
    __syncthreads();

    float dL = 0.0f, dC = 0.0f, dNP = 0.0f, dM = 0.0f;
    if (lane < O_NUM) {
        int a = s_bp[wid][lane];
        bool owner = true;
        for (int o2 = lane + 1; o2 < O_NUM; ++o2)
            if (s_bp[wid][o2] == a) owner = false;
        if (owner) {
            float4 pr = *(const float4*)(anchors + (size_t)a * 4);
            float hw = pr.z * 0.5f, hh = pr.w * 0.5f;
            float px1 = pr.x - hw, py1 = pr.y - hh;
            float px2 = pr.x + hw, py2 = pr.y + hh;
            float apn = (px2 - px1) * (py2 - py1);
            unsigned int bk = 0u;
            for (int o2 = 0; o2 < O_NUM; ++o2) {
                float4 t = s_tc[wid][o2];
                unsigned int hi = iou_hi(t.x, t.y, t.z, t.w, s_ta[wid][o2], px1, py1, px2, py2, apn);
                bk = max(bk, hi | (unsigned int)(31 - o2));
            }
            int old_o = 31 - (int)(bk & 31u);
            unsigned int old_hi = bk & 0xFFFFC000u;
            int old_cv = (old_hi >= 0x3F000000u) ? (int)s_lab[wid][old_o] + 1 : 0;
            const float2 cdv = *(const float2*)(conf_data + ((size_t)frame * A_NUM + a) * 2);
            int pred = (cdv.y > cdv.x) ? 1 : 0;
            float4 ld = *(const float4*)(loc_data + ((size_t)frame * A_NUM + a) * 4);
            int new_cv = (int)s_lab[wid][lane] + 1;
            dL = sl1_sum(s_tc[wid][lane], pr, ld);
            dC = bce_pos(pred, (float)new_cv);
            dNP = 1.0f;
            if (old_cv > 0) {
                dL -= sl1_sum(s_tc[wid][old_o], pr, ld);
                dC -= bce_pos(pred, (float)old_cv);
                dNP -= 1.0f;
            } else {
                dM -= (float)pred;
            }
        }
    }
    for (int s = 32; s > 0; s >>= 1) {
        dL += __shfl_down(dL, s);
        dC += __shfl_down(dC, s);
        dNP += __shfl_down(dNP, s);
        dM += __shfl_down(dM, s);
    }
    if (lane == 0) {
        float L = 0, C = 0, NP = 0, M = 0;
        for (int s = 0; s < ASPLIT; ++s) {
            float4 p = g_part[frame * ASPLIT + s];
            L += p.x; C += p.y; NP += p.z; M += p.w;
        }
        L += dL; C += dC; NP += dNP; M += dM;
        int np = (int)NP, m = (int)M;
        int num_neg = min(NEGPOS * np, A_NUM - 1);
        int nsel = min(num_neg, m);
        ws_l[frame] = L;
        ws_c[frame] = C + 27.631021115928547f * (float)nsel;
    }
}

__global__ void mfbl_k3(const float* __restrict__ ws_l, const float* __restrict__ ws_c,
                        float* __restrict__ out, int n) {
    int tid = threadIdx.x;
    float a = (tid < n) ? ws_l[tid] : 0.0f;
    float b = (tid < n) ? ws_c[tid] : 0.0f;
    for (int s = 32; s > 0; s >>= 1) {
        a += __shfl_down(a, s);
        b += __shfl_down(b, s);
    }
    __shared__ float sa[4], sb[4];
    int lane = tid & 63, wid = tid >> 6;
    if (lane == 0) { sa[wid] = a; sb[wid] = b; }
    __syncthreads();
    if (tid == 0) {
        float A = 0.0f, B = 0.0f;
        for (int w = 0; w < 4; ++w) { A += sa[w]; B += sb[w]; }
        out[0] = A;
        out[1] = B;
    }
}

// ---------------- diagnostic probes (outputs go to dead scratch only) ----------------
// MODE 0: reference hot loop.  MODE 1: rcp -> mul.  MODE 2: no per-truth tb chain.
// MODE 3: DPP rotation -> opaque v_mov (no lane crossbar).
template<int MODE>
__global__ __launch_bounds__(NTHR) void mfbl_probe(
    const float* __restrict__ anchors, const float* __restrict__ targets,
    unsigned int* __restrict__ sink)
{
    const int frame = blockIdx.x;
    const int nA = APB;
    const int tid = threadIdx.x;
    const int lane = tid & 63;
    const int r = lane >> 4, i = lane & 15;

    __shared__ float4 s_tc[O_NUM];
    if (tid < O_NUM) {
        const float* t = targets + ((size_t)frame * O_NUM + tid) * 5;
        s_tc[tid] = make_float4(t[0], t[1], t[2], t[3]);
    }
    float px1[K_ANCH], py1[K_ANCH], px2[K_ANCH], py2[K_ANCH], ap[K_ANCH];
    unsigned int bestA[K_ANCH];
#pragma unroll
    for (int k = 0; k < K_ANCH; ++k) {
        int idx = tid + k * NTHR;
        int ic = min(idx, nA - 1);
        float4 pr = *(const float4*)(anchors + (size_t)ic * 4);
        float hw = pr.z * 0.5f, hh = pr.w * 0.5f;
        px1[k] = pr.x - hw; py1[k] = pr.y - hh;
        px2[k] = pr.x + hw; py2[k] = pr.y + hh;
        ap[k] = (px2[k] - px1[k]) * (py2[k] - py1[k]);
        bestA[k] = 0u;
    }
    const unsigned int aT0 = 16383u - (unsigned int)tid;
    __syncthreads();

    unsigned int acc = 0u;
    for (int p = 0; p < 2; ++p) {
        const int t0 = (((r + p) & 1) << 4) | i;
        float4 tc = s_tc[t0];
        float ta = (tc.z - tc.x) * (tc.w - tc.y);
        unsigned int oc = (unsigned int)(31 - t0);
        unsigned int tb = 0u;
        for (int s = 0; s < 16; ++s) {
#pragma unroll
            for (int k = 0; k < K_ANCH; ++k) {
                float w = __saturatef(fminf(tc.z, px2[k]) - fmaxf(tc.x, px1[k]));
                float h = __saturatef(fminf(tc.w, py2[k]) - fmaxf(tc.y, py1[k]));
                float inter = w * h;
                float uni = (ta + ap[k]) - inter;
                float iou;
                if constexpr (MODE == 1) iou = inter * uni;                       // no trans op
                else                     iou = inter * __builtin_amdgcn_rcpf(uni);
                unsigned int hi = __float_as_uint(iou) & 0xFFFFC000u;
                bestA[k] = max(bestA[k], hi | oc);
                if constexpr (MODE != 2) tb = max(tb, hi | (aT0 - (unsigned int)(k * NTHR)));
            }
            if constexpr (MODE == 3) {
                asm volatile("v_mov_b32 %0, %1" : "=v"(tc.x) : "v"(tc.x));
                asm volatile("v_mov_b32 %0, %1" : "=v"(tc.y) : "v"(tc.y));
                asm volatile("v_mov_b32 %0, %1" : "=v"(tc.z) : "v"(tc.z));
                asm volatile("v_mov_b32 %0, %1" : "=v"(tc.w) : "v"(tc.w));
                asm volatile("v_mov_b32 %0, %1" : "=v"(ta)   : "v"(ta));
                asm volatile("v_mov_b32 %0, %1" : "=v"(oc)   : "v"(oc));
                asm volatile("v_mov_b32 %0, %1" : "=v"(tb)   : "v"(tb));
            } else {
                tc.x = rotf(tc.x); tc.y = rotf(tc.y);
                tc.z = rotf(tc.z); tc.w = rotf(tc.w);
                ta = rotf(ta); oc = rotu(oc);
                if constexpr (MODE != 2) tb = rotu(tb);
            }
        }
        acc ^= tb;
    }
#pragma unroll
    for (int k = 0; k < K_ANCH; ++k) acc ^= bestA[k];
    sink[(((unsigned)blockIdx.x << 8) + (unsigned)tid) & 8191u] = acc;  // dead scratch
}

extern "C" void kernel_launch(void* const* d_in, const int* in_sizes, int n_in,
                              void* d_out, int out_size, void* d_ws, size_t ws_size,
                              hipStream_t stream) {
    const float* loc     = (const float*)d_in[0];
    const float* conf    = (const float*)d_in[1];
    const float* anchors = (const float*)d_in[2];
    const float* targets = (const float*)d_in[3];
    float* out = (float*)d_out;
    (void)ws_size;

    const int BF = in_sizes[3] / (O_NUM * 5);   // 256 frames

    unsigned int* g_tred = (unsigned int*)d_ws;                                   // BF*32 u32
    float4* g_part = (float4*)((char*)d_ws + (size_t)BF * O_NUM * 4);             // BF*ASPLIT float4
    float* ws_l = (float*)((char*)g_part + (size_t)BF * ASPLIT * 16);
    float* ws_c = ws_l + BF;
    unsigned int* sink = (unsigned int*)((char*)d_ws + (100 << 10));              // dead scratch (32 KB)

    hipMemsetAsync(g_tred, 0, (size_t)BF * O_NUM * 4, stream);                    // capture-safe
    mfbl_k1<<<dim3(ASPLIT, BF), NTHR, 0, stream>>>(loc, conf, anchors, targets, g_tred, g_part);
    mfbl_k2<<<BF / 4, 256, 0, stream>>>(loc, conf, anchors, targets, g_tred, g_part, ws_l, ws_c);
    mfbl_k3<<<1, 256, 0, stream>>>(ws_l, ws_c, out, BF);

    // diagnostic probes — run AFTER k3 so they may clobber any ws region; results unread
    mfbl_probe<0><<<256, NTHR, 0, stream>>>(anchors, targets, sink);
    mfbl_probe<1><<<256, NTHR, 0, stream>>>(anchors, targets, sink);
    mfbl_probe<2><<<256, NTHR, 0, stream>>>(anchors, targets, sink);
    mfbl_probe<3><<<256, NTHR, 0, stream>>>(anchors, targets, sink);
}

// Round 14
// 75.431 us; speedup vs baseline: 1.8802x; 1.8802x over previous
//
#include <hip/hip_runtime.h>
#include <math.h>

#define A_NUM 8732
#define O_NUM 32
#define NEGPOS 3
#define NTHR 256
#define NWAVE 4
#define ASPLIT 4
#define APB 2183                       // 8732/4 exactly
#define K_ANCH 9                       // 9*256 = 2304 >= 2183
#define LOGEPS_F (-27.631021115928547f)

__device__ __forceinline__ unsigned int rotu(unsigned int v) {
    // row_ror:1 (0x121): rotate by 1 within each 16-lane row
    return (unsigned int)__builtin_amdgcn_update_dpp((int)v, (int)v, 0x121, 0xf, 0xf, false);
}
__device__ __forceinline__ float rotf(float v) {
    return __int_as_float((int)rotu((unsigned int)__float_as_int(v)));
}

// top-18 bits of IoU as a uint (IoU >= 0 so uint order == float order)
__device__ __forceinline__ unsigned int iou_hi(float tx1, float ty1, float tx2, float ty2, float ta,
                                               float px1, float py1, float px2, float py2, float ap) {
    float w = __saturatef(fminf(tx2, px2) - fmaxf(tx1, px1));
    float h = __saturatef(fminf(ty2, py2) - fmaxf(ty1, py1));
    float inter = w * h;
    float uni = (ta + ap) - inter;
    float iou = inter * __builtin_amdgcn_rcpf(uni);
    return __float_as_uint(iou) & 0xFFFFC000u;
}

__device__ __forceinline__ float sl1_sum(float4 t, float4 pr, float4 ld) {
    float gx = ((t.x + t.z) * 0.5f - pr.x) / (0.1f * pr.z);
    float gy = ((t.y + t.w) * 0.5f - pr.y) / (0.1f * pr.w);
    float gw = logf((t.z - t.x) / pr.z) / 0.2f;
    float gh = logf((t.w - t.y) / pr.w) / 0.2f;
    float d0 = ld.x - gx, d1 = ld.y - gy, d2 = ld.z - gw, d3 = ld.w - gh;
    float a0 = fabsf(d0), a1 = fabsf(d1), a2 = fabsf(d2), a3 = fabsf(d3);
    float s0 = (a0 < 1.0f) ? 0.5f * d0 * d0 : a0 - 0.5f;
    float s1 = (a1 < 1.0f) ? 0.5f * d1 * d1 : a1 - 0.5f;
    float s2 = (a2 < 1.0f) ? 0.5f * d2 * d2 : a2 - 0.5f;
    float s3 = (a3 < 1.0f) ? 0.5f * d3 * d3 : a3 - 0.5f;
    return s0 + s1 + s2 + s3;
}

__device__ __forceinline__ float bce_pos(int pred, float tgt) {
    float logp   = (pred == 0) ? LOGEPS_F : 0.0f;
    float log1mp = (pred == 1) ? LOGEPS_F : 0.0f;
    return -(tgt * logp + (1.0f - tgt) * log1mp);
}

// K1: grid = (ASPLIT, BF) = 1024 blocks of 256 threads (4 waves).
// Anchors pinned in lane VGPRs (K_ANCH each); truths rotate through lanes via
// DPP. Hot loop touches no memory. Per-truth split keys stored NON-atomically
// (g_tred[frame][split][truth]); k2 reduces the 4 splits -> no memset needed.
__global__ __launch_bounds__(NTHR) void mfbl_k1(
    const float* __restrict__ loc_data, const float* __restrict__ conf_data,
    const float* __restrict__ anchors, const float* __restrict__ targets,
    unsigned int* __restrict__ g_tred, float4* __restrict__ g_part)
{
    const int split = blockIdx.x;
    const int frame = blockIdx.y;
    const int a_lo = split * APB;
    const int nA = min(a_lo + APB, A_NUM) - a_lo;   // 2183
    const int tid = threadIdx.x;
    const int lane = tid & 63;
    const int wid  = tid >> 6;
    const int r = lane >> 4;                         // row 0..3
    const int i = lane & 15;                         // in-row pos

    __shared__ float4 s_tc[O_NUM];
    __shared__ float  s_lab[O_NUM];
    __shared__ unsigned int s_tred[O_NUM][NWAVE];
    __shared__ float s_r[4][NWAVE];

    if (tid < O_NUM) {
        const float* t = targets + ((size_t)frame * O_NUM + tid) * 5;
        s_tc[tid] = make_float4(t[0], t[1], t[2], t[3]);
        s_lab[tid] = t[4];
    }

    // pin K_ANCH anchors per lane in registers (clamped dup loads for overflow
    // lanes; their per-truth keys carry a strictly smaller aT so they never win)
    float px1[K_ANCH], py1[K_ANCH], px2[K_ANCH], py2[K_ANCH], ap[K_ANCH];
    unsigned int bestA[K_ANCH];
#pragma unroll
    for (int k = 0; k < K_ANCH; ++k) {
        int idx = tid + k * NTHR;
        int ic = min(idx, nA - 1);
        float4 pr = *(const float4*)(anchors + (size_t)(a_lo + ic) * 4);
        float hw = pr.z * 0.5f, hh = pr.w * 0.5f;
        px1[k] = pr.x - hw; py1[k] = pr.y - hh;
        px2[k] = pr.x + hw; py2[k] = pr.y + hh;
        ap[k] = (px2[k] - px1[k]) * (py2[k] - py1[k]);
        bestA[k] = 0u;
    }
    const unsigned int aT0 = 16383u - (unsigned int)(a_lo + tid);  // aT[k] = aT0 - k*NTHR
    __syncthreads();

    // ---------- hot loop: 2 phases x 16 systolic rotation steps ----------
    unsigned int tbp[2];
    for (int p = 0; p < 2; ++p) {
        const int t0 = (((r + p) & 1) << 4) | i;     // my starting truth
        float4 tc = s_tc[t0];
        float ta = (tc.z - tc.x) * (tc.w - tc.y);
        unsigned int oc = (unsigned int)(31 - t0);
        unsigned int tb = 0u;
        for (int s = 0; s < 16; ++s) {
#pragma unroll
            for (int k = 0; k < K_ANCH; ++k) {
                unsigned int hi = iou_hi(tc.x, tc.y, tc.z, tc.w, ta,
                                         px1[k], py1[k], px2[k], py2[k], ap[k]);
                bestA[k] = max(bestA[k], hi | oc);
                tb = max(tb, hi | (aT0 - (unsigned int)(k * NTHR)));
            }
            tc.x = rotf(tc.x); tc.y = rotf(tc.y);
            tc.z = rotf(tc.z); tc.w = rotf(tc.w);
            ta = rotf(ta); oc = rotu(oc); tb = rotu(tb);
        }
        tbp[p] = tb;   // 16 rotations = identity: tb is home
    }

    // combine per-truth partials: 4 copies (2 rows x 2 phases) per truth
    unsigned int v = max(tbp[0], (unsigned int)__shfl_xor((int)tbp[1], 16));
    v = max(v, (unsigned int)__shfl_xor((int)v, 32));
    if (lane < O_NUM) s_tred[lane][wid] = v;         // lane < 32 holds truth 'lane'
    __syncthreads();
    if (tid < O_NUM) {
        unsigned int k = s_tred[tid][0];
        for (int w = 1; w < NWAVE; ++w) k = max(k, s_tred[tid][w]);
        g_tred[((size_t)frame * ASPLIT + split) * O_NUM + tid] = k;  // plain store
    }

    // ---------- pass 2: unforced contributions (anchors still in regs) ----------
    float l_sum = 0.0f, cpos = 0.0f, np_cnt = 0.0f, m_cnt = 0.0f;
#pragma unroll
    for (int k = 0; k < K_ANCH; ++k) {
        int idx = tid + k * NTHR;
        if (idx < nA) {
            unsigned int key = bestA[k];
            int bo = 31 - (int)(key & 31u);
            unsigned int hi = key & 0xFFFFC000u;
            int a = a_lo + idx;
            const float2 cdv = *(const float2*)(conf_data + ((size_t)frame * A_NUM + a) * 2);
            int pred = (cdv.y > cdv.x) ? 1 : 0;
            int cv = (hi >= 0x3F000000u) ? (int)s_lab[bo] + 1 : 0;
            if (cv > 0) {
                np_cnt += 1.0f;
                float4 pr = *(const float4*)(anchors + (size_t)a * 4);
                float4 ld = *(const float4*)(loc_data + ((size_t)frame * A_NUM + a) * 4);
                l_sum += sl1_sum(s_tc[bo], pr, ld);
                cpos += bce_pos(pred, (float)cv);
            } else {
                m_cnt += (float)pred;     // negative with lc > log2 <=> pred==1
            }
        }
    }
    for (int s = 32; s > 0; s >>= 1) {
        l_sum  += __shfl_down(l_sum, s);
        cpos   += __shfl_down(cpos, s);
        np_cnt += __shfl_down(np_cnt, s);
        m_cnt  += __shfl_down(m_cnt, s);
    }
    if (lane == 0) { s_r[0][wid] = l_sum; s_r[1][wid] = cpos; s_r[2][wid] = np_cnt; s_r[3][wid] = m_cnt; }
    __syncthreads();
    if (tid == 0) {
        float L = 0, C = 0, NP = 0, M = 0;
        for (int w = 0; w < NWAVE; ++w) { L += s_r[0][w]; C += s_r[1][w]; NP += s_r[2][w]; M += s_r[3][w]; }
        g_part[frame * ASPLIT + split] = make_float4(L, C, NP, M);
    }
}

// K2: grid = BF/4 blocks x 256 threads; one frame per wave.
// Reduce per-split keys, forced-match corrections (<=32 anchors/frame), finalize.
__global__ __launch_bounds__(256) void mfbl_k2(
    const float* __restrict__ loc_data, const float* __restrict__ conf_data,
    const float* __restrict__ anchors, const float* __restrict__ targets,
    const unsigned int* __restrict__ g_tred, const float4* __restrict__ g_part,
    float* __restrict__ ws_l, float* __restrict__ ws_c)
{
    const int lane = threadIdx.x & 63;
    const int wid  = threadIdx.x >> 6;
    const int frame = blockIdx.x * 4 + wid;

    __shared__ float4 s_tc[4][O_NUM];
    __shared__ float s_ta[4][O_NUM], s_lab[4][O_NUM];
    __shared__ int s_bp[4][O_NUM];

    if (lane < O_NUM) {
        const float* t = targets + ((size_t)frame * O_NUM + lane) * 5;
        float x1 = t[0], y1 = t[1], x2 = t[2], y2 = t[3];
        s_tc[wid][lane] = make_float4(x1, y1, x2, y2);
        s_ta[wid][lane] = (x2 - x1) * (y2 - y1);
        s_lab[wid][lane] = t[4];
        unsigned int k = 0u;
        for (int s = 0; s < ASPLIT; ++s)
            k = max(k, g_tred[((size_t)frame * ASPLIT + s) * O_NUM + lane]);
        s_bp[wid][lane] = 16383 - (int)(k & 16383u);
    }
    __syncthreads();

    float dL = 0.0f, dC = 0.0f, dNP = 0.0f, dM = 0.0f;
    if (lane < O_NUM) {
        int a = s_bp[wid][lane];
        bool owner = true;                       // last truth writing this anchor wins
        for (int o2 = lane + 1; o2 < O_NUM; ++o2)
            if (s_bp[wid][o2] == a) owner = false;
        if (owner) {
            float4 pr = *(const float4*)(anchors + (size_t)a * 4);
            float hw = pr.z * 0.5f, hh = pr.w * 0.5f;
            float px1 = pr.x - hw, py1 = pr.y - hh;
            float px2 = pr.x + hw, py2 = pr.y + hh;
            float apn = (px2 - px1) * (py2 - py1);
            unsigned int bk = 0u;                // recompute unforced best truth
            for (int o2 = 0; o2 < O_NUM; ++o2) {
                float4 t = s_tc[wid][o2];
                unsigned int hi = iou_hi(t.x, t.y, t.z, t.w, s_ta[wid][o2], px1, py1, px2, py2, apn);
                bk = max(bk, hi | (unsigned int)(31 - o2));
            }
            int old_o = 31 - (int)(bk & 31u);
            unsigned int old_hi = bk & 0xFFFFC000u;
            int old_cv = (old_hi >= 0x3F000000u) ? (int)s_lab[wid][old_o] + 1 : 0;
            const float2 cdv = *(const float2*)(conf_data + ((size_t)frame * A_NUM + a) * 2);
            int pred = (cdv.y > cdv.x) ? 1 : 0;
            float4 ld = *(const float4*)(loc_data + ((size_t)frame * A_NUM + a) * 4);
            int new_cv = (int)s_lab[wid][lane] + 1;
            dL = sl1_sum(s_tc[wid][lane], pr, ld);
            dC = bce_pos(pred, (float)new_cv);
            dNP = 1.0f;
            if (old_cv > 0) {
                dL -= sl1_sum(s_tc[wid][old_o], pr, ld);
                dC -= bce_pos(pred, (float)old_cv);
                dNP -= 1.0f;
            } else {
                dM -= (float)pred;
            }
        }
    }
    for (int s = 32; s > 0; s >>= 1) {
        dL += __shfl_down(dL, s);
        dC += __shfl_down(dC, s);
        dNP += __shfl_down(dNP, s);
        dM += __shfl_down(dM, s);
    }
    if (lane == 0) {
        float L = 0, C = 0, NP = 0, M = 0;
        for (int s = 0; s < ASPLIT; ++s) {
            float4 p = g_part[frame * ASPLIT + s];
            L += p.x; C += p.y; NP += p.z; M += p.w;
        }
        L += dL; C += dC; NP += dNP; M += dM;
        int np = (int)NP, m = (int)M;
        int num_neg = min(NEGPOS * np, A_NUM - 1);
        int nsel = min(num_neg, m);
        ws_l[frame] = L;
        ws_c[frame] = C + 27.631021115928547f * (float)nsel;
    }
}

__global__ void mfbl_k3(const float* __restrict__ ws_l, const float* __restrict__ ws_c,
                        float* __restrict__ out, int n) {
    int tid = threadIdx.x;
    float a = (tid < n) ? ws_l[tid] : 0.0f;
    float b = (tid < n) ? ws_c[tid] : 0.0f;
    for (int s = 32; s > 0; s >>= 1) {
        a += __shfl_down(a, s);
        b += __shfl_down(b, s);
    }
    __shared__ float sa[4], sb[4];
    int lane = tid & 63, wid = tid >> 6;
    if (lane == 0) { sa[wid] = a; sb[wid] = b; }
    __syncthreads();
    if (tid == 0) {
        float A = 0.0f, B = 0.0f;
        for (int w = 0; w < 4; ++w) { A += sa[w]; B += sb[w]; }
        out[0] = A;
        out[1] = B;
    }
}

extern "C" void kernel_launch(void* const* d_in, const int* in_sizes, int n_in,
                              void* d_out, int out_size, void* d_ws, size_t ws_size,
                              hipStream_t stream) {
    const float* loc     = (const float*)d_in[0];
    const float* conf    = (const float*)d_in[1];
    const float* anchors = (const float*)d_in[2];
    const float* targets = (const float*)d_in[3];
    float* out = (float*)d_out;
    (void)ws_size;

    const int BF = in_sizes[3] / (O_NUM * 5);   // 256 frames

    unsigned int* g_tred = (unsigned int*)d_ws;                                   // BF*ASPLIT*32 u32 (128 KB)
    float4* g_part = (float4*)((char*)d_ws + (size_t)BF * ASPLIT * O_NUM * 4);    // BF*ASPLIT float4
    float* ws_l = (float*)((char*)g_part + (size_t)BF * ASPLIT * 16);
    float* ws_c = ws_l + BF;

    mfbl_k1<<<dim3(ASPLIT, BF), NTHR, 0, stream>>>(loc, conf, anchors, targets, g_tred, g_part);
    mfbl_k2<<<BF / 4, 256, 0, stream>>>(loc, conf, anchors, targets, g_tred, g_part, ws_l, ws_c);
    mfbl_k3<<<1, 256, 0, stream>>>(ws_l, ws_c, out, BF);
}